// Round 14
// baseline (179.205 us; speedup 1.0000x reference)
//
#include <hip/hip_runtime.h>
#include <cstddef>

// ---- problem constants ----
#define B_   16
#define C_   256
#define HW_  1024
#define NH_  4
#define NG_  32
#define CPG_ 8          // channels per group
#define CS_  0.18033688f   // 0.125 * log2(e), folded into Q at QKV epilogue

typedef __attribute__((ext_vector_type(8))) short bf16x8;
typedef __attribute__((ext_vector_type(4))) short s16x4;
typedef __attribute__((ext_vector_type(8))) _Float16 f16x8;
typedef __attribute__((ext_vector_type(4))) float f32x4;

#define MFMA16B(a, b, c) __builtin_amdgcn_mfma_f32_16x16x32_bf16(a, b, c, 0, 0, 0)
#define MFMA16H(a, b, c) __builtin_amdgcn_mfma_f32_16x16x32_f16(a, b, c, 0, 0, 0)

#if __has_builtin(__builtin_amdgcn_mfma_f32_16x16x16bf16_1k)
#define HAVE_MFMA16K16 1
#define MFMA16B4(a, b, c) __builtin_amdgcn_mfma_f32_16x16x16bf16_1k(a, b, c, 0, 0, 0)
#else
#define HAVE_MFMA16K16 0
#endif

// ---- bf16 <-> f32 helpers ----
__device__ __forceinline__ float bf2f(unsigned short h) {
    unsigned int u = ((unsigned int)h) << 16;
    return __builtin_bit_cast(float, u);
}
__device__ __forceinline__ unsigned short f2bf(float f) {
    unsigned int u = __builtin_bit_cast(unsigned int, f);
    u += 0x7FFFu + ((u >> 16) & 1u);   // round-to-nearest-even
    return (unsigned short)(u >> 16);
}
#if __has_builtin(__builtin_amdgcn_cvt_pk_bf16_f32)
__device__ __forceinline__ unsigned packbf(float a, float b) {
    auto v = __builtin_amdgcn_cvt_pk_bf16_f32(a, b);   // lo=a, hi=b
    return __builtin_bit_cast(unsigned, v);
}
#else
__device__ __forceinline__ unsigned packbf(float a, float b) {
    unsigned ua = __builtin_bit_cast(unsigned, a) + 0x8000u;
    unsigned ub = __builtin_bit_cast(unsigned, b) + 0x8000u;
    return __builtin_amdgcn_perm(ub, ua, 0x07060302u);
}
#endif
__device__ __forceinline__ unsigned pkh(float a, float b) {
    auto h2 = __builtin_amdgcn_cvt_pkrtz(a, b);   // __fp16 ext_vector(2)
    return __builtin_bit_cast(unsigned, h2);
}

// =====================================================================
// Fused GN-apply + weight-convert.
// Blocks 0..511: GroupNorm (b,g): stats, then write y16 = f16(GN(x)).
// Blocks 512..767: fp32->f16 weight conversion.
// =====================================================================
__global__ __launch_bounds__(256) void gn_wcvt_kernel(
    const float* __restrict__ x,
    const float* __restrict__ gw,
    const float* __restrict__ gb,
    unsigned short* __restrict__ y16,       // f16 [B*C*HW]
    const float* __restrict__ qw, const float* __restrict__ pw,
    unsigned short* __restrict__ oq, unsigned short* __restrict__ op)
{
    if (blockIdx.x >= 512) {
        int i = (blockIdx.x - 512) * 256 + threadIdx.x;   // 65536 float4s
        const float* s; unsigned short* d; int j;
        if (i < 49152) { s = qw; d = oq; j = i; }
        else           { s = pw; d = op; j = i - 49152; }
        float4 f = ((const float4*)s)[j];
        uint2 u = {pkh(f.x, f.y), pkh(f.z, f.w)};
        *(uint2*)&d[(size_t)j * 4] = u;
        return;
    }
    int blk = blockIdx.x;                 // b*NG + g
    const size_t base = (size_t)blk * CPG_ * HW_;
    const float* xg = x + base;
    const int N = CPG_ * HW_;             // 8192

    float s = 0.f, ss = 0.f;
    for (int e = threadIdx.x * 4; e < N; e += 1024) {
        float4 v4 = *(const float4*)&xg[e];
        s  += v4.x + v4.y + v4.z + v4.w;
        ss += v4.x * v4.x + v4.y * v4.y + v4.z * v4.z + v4.w * v4.w;
    }
    #pragma unroll
    for (int off = 32; off > 0; off >>= 1) {
        s  += __shfl_down(s, off, 64);
        ss += __shfl_down(ss, off, 64);
    }
    __shared__ float red[8];
    __shared__ float2 stf;
    int lane = threadIdx.x & 63, wv = threadIdx.x >> 6;
    if (lane == 0) { red[wv] = s; red[4 + wv] = ss; }
    __syncthreads();
    if (threadIdx.x == 0) {
        float S  = red[0] + red[1] + red[2] + red[3];
        float SS = red[4] + red[5] + red[6] + red[7];
        float mean = S / (float)N;
        float var  = SS / (float)N - mean * mean;
        stf = make_float2(mean, rsqrtf(var + 1e-5f));
    }
    __syncthreads();
    float mean = stf.x, rstd = stf.y;
    for (int e = threadIdx.x * 4; e < N; e += 1024) {
        int ch = (blk & 31) * CPG_ + (e >> 10);
        float sc = rstd * gw[ch];
        float sh = gb[ch] - mean * sc;
        float4 v4 = *(const float4*)&xg[e];
        uint2 u;
        u.x = pkh(v4.x * sc + sh, v4.y * sc + sh);
        u.y = pkh(v4.z * sc + sh, v4.w * sc + sh);
        *(uint2*)&y16[base + e] = u;
    }
}

// =====================================================================
// QKV MFMA GEMM R14 (f16, fp32 accum): tile 256m x 64n x 32k, dbuf LDS,
// one barrier per K-step. 4 waves stacked in m (64m x 64n each).
// B reads pre-normalized y16 (pure pack, no GN math). m-tile = entire
// Q (m0=0, scaled CS_), K (m0=256) or V (m0=512) -> uniform epilogue.
// Grid (16 n, 3 m, 16 b) = 768 blocks = 3 blocks/CU.
// =====================================================================
__global__ __launch_bounds__(256) void qkv_mfma_kernel(
    const unsigned short* __restrict__ W16,
    const unsigned short* __restrict__ y16,  // f16 [B*256][1024]
    const float* __restrict__ bias,
    unsigned short* __restrict__ qT,   // bf16 [B*4][1024][64]
    unsigned short* __restrict__ kT,   // bf16 [B*4][1024][64]
    unsigned short* __restrict__ vN)   // bf16 [B*256][1024]
{
    const int K = 256, N = 1024;
    __shared__ union {
        struct { unsigned short A[2][256][40]; unsigned short Bt[2][64][40]; } st;
        unsigned short nd[64][288];   // Q/K epilogue: [n][h*72 + d] (bank-skewed)
        unsigned short mn[256][72];   // V epilogue:   [m][n]
    } L;

    const int b  = blockIdx.z;
    const int m0 = blockIdx.y * 256, n0 = blockIdx.x * 64;
    const int t  = threadIdx.x;
    const int l15 = t & 15, quad = (t >> 4) & 3;
    const int wm = t >> 6;            // wave 0..3 = m-quarter

    union HF { uint4 q; f16x8 v; };

    f32x4 acc[4][4];
    #pragma unroll
    for (int mt = 0; mt < 4; ++mt)
        #pragma unroll
        for (int nt = 0; nt < 4; ++nt)
            acc[mt][nt] = (f32x4){0.f, 0.f, 0.f, 0.f};

    const int bn = t & 63, bkb = t >> 6;   // B: n, k-block(8)

    uint4 pa[4];               // A prefetch: row (m0+t), 32 f16
    unsigned short ph[8];      // B prefetch: 8 k of column n0+bn

    auto PREF = [&](int k0) {
        const unsigned short* wp = &W16[(size_t)(m0 + t) * K + k0];
        pa[0] = *(const uint4*)(wp);
        pa[1] = *(const uint4*)(wp + 8);
        pa[2] = *(const uint4*)(wp + 16);
        pa[3] = *(const uint4*)(wp + 24);
        int ch = k0 + bkb * 8;
        const unsigned short* xp = &y16[((size_t)b * 256 + ch) * 1024 + n0 + bn];
        #pragma unroll
        for (int j = 0; j < 8; ++j) ph[j] = xp[(size_t)j * 1024];
    };

    PREF(0);
    #pragma unroll 1
    for (int it = 0; it < 8; ++it) {
        const int bsel = it & 1;
        *(uint4*)&L.st.A[bsel][t][0]  = pa[0];
        *(uint4*)&L.st.A[bsel][t][8]  = pa[1];
        *(uint4*)&L.st.A[bsel][t][16] = pa[2];
        *(uint4*)&L.st.A[bsel][t][24] = pa[3];
        {
            uint4 bw;
            bw.x = (unsigned)ph[0] | ((unsigned)ph[1] << 16);
            bw.y = (unsigned)ph[2] | ((unsigned)ph[3] << 16);
            bw.z = (unsigned)ph[4] | ((unsigned)ph[5] << 16);
            bw.w = (unsigned)ph[6] | ((unsigned)ph[7] << 16);
            *(uint4*)&L.st.Bt[bsel][bn][bkb * 8] = bw;
        }
        __syncthreads();
        if (it + 1 < 8) PREF((it + 1) * 32);
        HF af[4], bfv[4];
        #pragma unroll
        for (int mt = 0; mt < 4; ++mt)
            af[mt].q = *(const uint4*)&L.st.A[bsel][wm * 64 + mt * 16 + l15][quad * 8];
        #pragma unroll
        for (int nt = 0; nt < 4; ++nt)
            bfv[nt].q = *(const uint4*)&L.st.Bt[bsel][nt * 16 + l15][quad * 8];
        #pragma unroll
        for (int mt = 0; mt < 4; ++mt)
            #pragma unroll
            for (int nt = 0; nt < 4; ++nt)
                acc[mt][nt] = MFMA16H(af[mt].v, bfv[nt].v, acc[mt][nt]);
    }
    __syncthreads();   // LDS union reused by epilogue

    if (m0 < 512) {
        // Q or K: whole tile is one of them. d = ml&63, h = ml>>6.
        const float qsc = (m0 == 0) ? CS_ : 1.f;
        #pragma unroll
        for (int mt = 0; mt < 4; ++mt)
            #pragma unroll
            for (int rr = 0; rr < 4; ++rr) {
                int ml = wm * 64 + mt * 16 + quad * 4 + rr;
                float bv = bias[m0 + ml];
                int skew = (ml >> 6) * 72 + (ml & 63);
                #pragma unroll
                for (int nt = 0; nt < 4; ++nt)
                    L.nd[nt * 16 + l15][skew] = f2bf((acc[mt][nt][rr] + bv) * qsc);
            }
        __syncthreads();
        unsigned short* dst = (m0 == 0) ? qT : kT;
        int n = t >> 2, h = t & 3;
        const unsigned short* src = &L.nd[n][h * 72];
        unsigned short* gp = &dst[((size_t)(b * 4 + h) * 1024 + n0 + n) * 64];
        #pragma unroll
        for (int u = 0; u < 8; ++u)
            *(uint4*)(gp + u * 8) = *(const uint4*)(src + u * 8);
    } else {
        // V: natural [b*256 + ch][n]
        #pragma unroll
        for (int mt = 0; mt < 4; ++mt)
            #pragma unroll
            for (int rr = 0; rr < 4; ++rr) {
                int ml = wm * 64 + mt * 16 + quad * 4 + rr;
                float bv = bias[m0 + ml];
                #pragma unroll
                for (int nt = 0; nt < 4; ++nt)
                    L.mn[ml][nt * 16 + l15] = f2bf(acc[mt][nt][rr] + bv);
            }
        __syncthreads();
        const unsigned short* src = &L.mn[t][0];
        unsigned short* gp = &vN[((size_t)b * 256 + t) * 1024 + n0];
        #pragma unroll
        for (int u = 0; u < 8; ++u)
            *(uint4*)(gp + u * 8) = *(const uint4*)(src + u * 8);
    }
}

// =====================================================================
// Proj MFMA GEMM (R13): tile 64m x 64n x 32k, grid 1024 (4 blocks/CU).
// B-stage fuses attention combine: (OP0+OP1) * 1/(l0+l1).
// out = fp32 d_out + bias + residual.
// =====================================================================
__global__ __launch_bounds__(256) void proj_mfma_kernel(
    const unsigned short* __restrict__ W16,
    const unsigned short* __restrict__ OP,   // bf16 [2][64][64][1024]
    const float* __restrict__ LPp,           // fp32 [2][64][1024]
    const float* __restrict__ bias,
    const float* __restrict__ res,
    float* __restrict__ outF)
{
    const int M = 256, K = 256, N = 1024;
    __shared__ struct { unsigned short A[2][64][40]; unsigned short Bt[2][64][40]; } L;

    const int b  = blockIdx.z;
    const int m0 = blockIdx.y * 64, n0 = blockIdx.x * 64;
    const int t  = threadIdx.x;
    const int l15 = t & 15, quad = (t >> 4) & 3;
    const int wave = t >> 6, wm = wave >> 1, wn = wave & 1;

    union HF { uint4 q; f16x8 v; };

    f32x4 acc[2][2];
    #pragma unroll
    for (int mt = 0; mt < 2; ++mt)
        #pragma unroll
        for (int nt = 0; nt < 2; ++nt)
            acc[mt][nt] = (f32x4){0.f, 0.f, 0.f, 0.f};

    const int ar = t >> 2, akh = (t & 3) * 8;      // A: 64 rows, 8 f16 each
    const int bn = t & 63, bkb = t >> 6;           // B: n, k-block(8)

    float rinv[4];
    {
        int n = n0 + bn;
        #pragma unroll
        for (int h = 0; h < 4; ++h) {
            float l0 = LPp[(size_t)(b * 4 + h) * 1024 + n];
            float l1 = LPp[(size_t)(64 + b * 4 + h) * 1024 + n];
            rinv[h] = 1.f / (l0 + l1);
        }
    }

    uint4 pa;
    unsigned short ph0[8], ph1[8];
    int pH = 0;

    auto PREF = [&](int k0) {
        pa = *(const uint4*)&W16[(size_t)(m0 + ar) * K + k0 + akh];
        int ch = k0 + bkb * 8;
        pH = ch >> 6;
        size_t base = ((size_t)(b * 4 + pH) * 64 + (ch & 63)) * 1024 + n0 + bn;
        #pragma unroll
        for (int j = 0; j < 8; ++j) {
            ph0[j] = OP[base + (size_t)j * 1024];
            ph1[j] = OP[(size_t)64 * 64 * 1024 + base + (size_t)j * 1024];
        }
    };

    PREF(0);
    #pragma unroll 1
    for (int it = 0; it < 8; ++it) {
        const int bsel = it & 1;
        *(uint4*)&L.A[bsel][ar][akh] = pa;
        {
            float ri = rinv[pH];
            float v[8];
            #pragma unroll
            for (int j = 0; j < 8; ++j)
                v[j] = (bf2f(ph0[j]) + bf2f(ph1[j])) * ri;
            uint4 bw = {pkh(v[0], v[1]), pkh(v[2], v[3]), pkh(v[4], v[5]), pkh(v[6], v[7])};
            *(uint4*)&L.Bt[bsel][bn][bkb * 8] = bw;
        }
        __syncthreads();
        if (it + 1 < 8) PREF((it + 1) * 32);
        HF af[2], bfv[2];
        #pragma unroll
        for (int mt = 0; mt < 2; ++mt)
            af[mt].q = *(const uint4*)&L.A[bsel][wm * 32 + mt * 16 + l15][quad * 8];
        #pragma unroll
        for (int nt = 0; nt < 2; ++nt)
            bfv[nt].q = *(const uint4*)&L.Bt[bsel][wn * 32 + nt * 16 + l15][quad * 8];
        #pragma unroll
        for (int mt = 0; mt < 2; ++mt)
            #pragma unroll
            for (int nt = 0; nt < 2; ++nt)
                acc[mt][nt] = MFMA16H(af[mt].v, bfv[nt].v, acc[mt][nt]);
    }

    #pragma unroll
    for (int mt = 0; mt < 2; ++mt) {
        #pragma unroll
        for (int rr = 0; rr < 4; ++rr) {
            int m = m0 + wm * 32 + mt * 16 + quad * 4 + rr;
            float bv = bias[m];
            #pragma unroll
            for (int nt = 0; nt < 2; ++nt) {
                int n = n0 + wn * 32 + nt * 16 + l15;
                size_t off = ((size_t)b * M + m) * (size_t)N + n;
                outF[off] = acc[mt][nt][rr] + bv + res[off];
            }
        }
    }
}

// =====================================================================
// MFMA flash attention (R12 structure): 128-q blocks, jh=2 split,
// dbuf LDS, one barrier/iter, register prefetch. PV via x16 MFMA
// (C-layout pack == x16 B-frag, no shuffles); l via ones-row MFMA.
// =====================================================================
__global__ __launch_bounds__(256) void attn_mfma_kernel(
    const unsigned short* __restrict__ qT,
    const unsigned short* __restrict__ kT,
    const unsigned short* __restrict__ vN,
    unsigned short* __restrict__ OP,   // [2][64][64][1024] bf16 unnormalized
    float* __restrict__ LP)            // [2][64][1024] fp32 partial l
{
    __shared__ unsigned short Kt[2][64][72];   // [buf][kv][d]
    __shared__ unsigned short Vs[2][64][72];   // [buf][d][kv]

    const int t    = threadIdx.x;
    const int wv   = t >> 6;
    const int l15  = t & 15;
    const int quad = (t >> 4) & 3;
    const int bh   = blockIdx.x;            // b*4 + h
    const int i0   = blockIdx.y * 128;
    const int jh   = blockIdx.z;            // kv half

    union FragU { uint4 q; unsigned u[4]; bf16x8 v; };

    FragU qf[2][2];
    {
        const unsigned short* qg = qT + (size_t)bh * (1024 * 64);
        int qrow = i0 + wv * 32 + l15;
        #pragma unroll
        for (int nt = 0; nt < 2; ++nt)
            #pragma unroll
            for (int kt = 0; kt < 2; ++kt)
                qf[nt][kt].q = *(const uint4*)&qg[(size_t)(qrow + nt * 16) * 64 + kt * 32 + quad * 8];
    }

    f32x4 accO[4][2];
    #pragma unroll
    for (int m = 0; m < 4; ++m)
        #pragma unroll
        for (int n = 0; n < 2; ++n)
            accO[m][n] = (f32x4){0.f, 0.f, 0.f, 0.f};
    float l_i[2] = {0.f, 0.f};
#if HAVE_MFMA16K16
    f32x4 accL[2] = {(f32x4){0.f, 0.f, 0.f, 0.f}, (f32x4){0.f, 0.f, 0.f, 0.f}};
    const s16x4 ones4 = {(short)0x3F80, (short)0x3F80, (short)0x3F80, (short)0x3F80};
#endif

    const unsigned short* kg = kT + (size_t)bh * (1024 * 64);
    const unsigned short* vg = vN + (size_t)bh * (64 * 1024);

    const int slbase = l15 + ((quad & 1) << 5);
    const bool upper = (t & 32) != 0;
    (void)slbase; (void)upper;
    const int sr = t >> 2, sc = (t & 3) * 16;

    uint4 kr0, kr1, vr0, vr1;
    {
        const int j0 = jh * 512;
        const unsigned short* kp = &kg[(size_t)(j0 + sr) * 64 + sc];
        const unsigned short* vp = &vg[(size_t)sr * 1024 + j0 + sc];
        kr0 = *(const uint4*)kp;  kr1 = *(const uint4*)(kp + 8);
        vr0 = *(const uint4*)vp;  vr1 = *(const uint4*)(vp + 8);
    }

    for (int it = 0; it < 8; ++it) {
        const int bsel = it & 1;
        *(uint4*)&Kt[bsel][sr][sc]     = kr0;
        *(uint4*)&Kt[bsel][sr][sc + 8] = kr1;
        *(uint4*)&Vs[bsel][sr][sc]     = vr0;
        *(uint4*)&Vs[bsel][sr][sc + 8] = vr1;
        __syncthreads();
        if (it < 7) {
            const int j0n = jh * 512 + (it + 1) * 64;
            const unsigned short* kp = &kg[(size_t)(j0n + sr) * 64 + sc];
            const unsigned short* vp = &vg[(size_t)sr * 1024 + j0n + sc];
            kr0 = *(const uint4*)kp;  kr1 = *(const uint4*)(kp + 8);
            vr0 = *(const uint4*)vp;  vr1 = *(const uint4*)(vp + 8);
        }

        // ---- S^T = K · Q^T ----
        f32x4 accS[4][2];
        #pragma unroll
        for (int mt = 0; mt < 4; ++mt) {
            FragU ak[2];
            #pragma unroll
            for (int kt = 0; kt < 2; ++kt)
                ak[kt].q = *(const uint4*)&Kt[bsel][mt * 16 + l15][kt * 32 + quad * 8];
            #pragma unroll
            for (int nt = 0; nt < 2; ++nt) {
                f32x4 z = (f32x4){0.f, 0.f, 0.f, 0.f};
                z = MFMA16B(ak[0].v, qf[nt][0].v, z);
                z = MFMA16B(ak[1].v, qf[nt][1].v, z);
                accS[mt][nt] = z;
            }
        }

#if HAVE_MFMA16K16
        union PB { unsigned u[2]; s16x4 v; };
        PB pb[4][2];
        #pragma unroll
        for (int mt = 0; mt < 4; ++mt)
            #pragma unroll
            for (int nt = 0; nt < 2; ++nt) {
                float p0 = exp2f(accS[mt][nt][0]);
                float p1 = exp2f(accS[mt][nt][1]);
                float p2 = exp2f(accS[mt][nt][2]);
                float p3 = exp2f(accS[mt][nt][3]);
                pb[mt][nt].u[0] = packbf(p0, p1);
                pb[mt][nt].u[1] = packbf(p2, p3);
            }
        #pragma unroll
        for (int mt = 0; mt < 4; ++mt)
            #pragma unroll
            for (int nt = 0; nt < 2; ++nt)
                accL[nt] = MFMA16B4(ones4, pb[mt][nt].v, accL[nt]);
        #pragma unroll
        for (int mtd = 0; mtd < 4; ++mtd) {
            union AV { uint2 d; s16x4 v; } av[4];
            #pragma unroll
            for (int mt = 0; mt < 4; ++mt)
                av[mt].d = *(const uint2*)&Vs[bsel][mtd * 16 + l15][mt * 16 + quad * 4];
            #pragma unroll
            for (int nt = 0; nt < 2; ++nt)
                #pragma unroll
                for (int mt = 0; mt < 4; ++mt)
                    accO[mtd][nt] = MFMA16B4(av[mt].v, pb[mt][nt].v, accO[mtd][nt]);
        }
#else
        float rs[2] = {0.f, 0.f};
        unsigned pk[4][2][2];
        #pragma unroll
        for (int mt = 0; mt < 4; ++mt)
            #pragma unroll
            for (int nt = 0; nt < 2; ++nt) {
                float p0 = exp2f(accS[mt][nt][0]);
                float p1 = exp2f(accS[mt][nt][1]);
                float p2 = exp2f(accS[mt][nt][2]);
                float p3 = exp2f(accS[mt][nt][3]);
                rs[nt] += (p0 + p1) + (p2 + p3);
                pk[mt][nt][0] = packbf(p0, p1);
                pk[mt][nt][1] = packbf(p2, p3);
            }
        #pragma unroll
        for (int nt = 0; nt < 2; ++nt) {
            float r = rs[nt];
            r += __shfl_xor(r, 16, 64);
            r += __shfl_xor(r, 32, 64);
            l_i[nt] += r;
        }
        FragU bfr[2][2];
        #pragma unroll
        for (int kt = 0; kt < 2; ++kt)
            #pragma unroll
            for (int nt = 0; nt < 2; ++nt)
                #pragma unroll
                for (int w4 = 0; w4 < 4; ++w4) {
                    int sl = slbase + ((w4 >> 1) << 4);
                    int lo = __shfl((int)pk[2 * kt + 0][nt][w4 & 1], sl, 64);
                    int hi = __shfl((int)pk[2 * kt + 1][nt][w4 & 1], sl, 64);
                    bfr[kt][nt].u[w4] = (unsigned)(upper ? hi : lo);
                }
        #pragma unroll
        for (int mtd = 0; mtd < 4; ++mtd) {
            FragU av[2];
            #pragma unroll
            for (int kt = 0; kt < 2; ++kt)
                av[kt].q = *(const uint4*)&Vs[bsel][mtd * 16 + l15][kt * 32 + quad * 8];
            #pragma unroll
            for (int nt = 0; nt < 2; ++nt) {
                accO[mtd][nt] = MFMA16B(av[0].v, bfr[0][nt].v, accO[mtd][nt]);
                accO[mtd][nt] = MFMA16B(av[1].v, bfr[1][nt].v, accO[mtd][nt]);
            }
        }
#endif
    }

#if HAVE_MFMA16K16
    l_i[0] = accL[0][0];
    l_i[1] = accL[1][0];
#endif

    unsigned short* ob = OP + ((size_t)jh * 64 + bh) * (64 * 1024) + i0 + wv * 32;
    #pragma unroll
    for (int mtd = 0; mtd < 4; ++mtd)
        #pragma unroll
        for (int nt = 0; nt < 2; ++nt)
            #pragma unroll
            for (int rr = 0; rr < 4; ++rr) {
                int d = mtd * 16 + quad * 4 + rr;
                ob[(size_t)d * 1024 + nt * 16 + l15] = f2bf(accO[mtd][nt][rr]);
            }
    if (quad == 0) {
        float* lp = &LP[((size_t)jh * 64 + bh) * 1024 + i0 + wv * 32 + l15];
        lp[0]  = l_i[0];
        lp[16] = l_i[1];
    }
}

// =====================================================================
extern "C" void kernel_launch(void* const* d_in, const int* in_sizes, int n_in,
                              void* d_out, int out_size, void* d_ws, size_t ws_size,
                              hipStream_t stream)
{
    const float* x      = (const float*)d_in[0];
    const float* gn_w   = (const float*)d_in[1];
    const float* gn_b   = (const float*)d_in[2];
    const float* qkv_w  = (const float*)d_in[3];
    const float* qkv_b  = (const float*)d_in[4];
    const float* proj_w = (const float*)d_in[5];
    const float* proj_b = (const float*)d_in[6];
    float* out = (float*)d_out;

    // ws: y16 8.4MB | w16q 384KB | w16p 128KB | qT/kT/vN 8MB each |
    //     OP 16.8MB | LP 512KB   (~50 MB total)
    char* ws = (char*)d_ws;
    unsigned short* y16  = (unsigned short*)ws;
    unsigned short* w16q = y16 + (size_t)B_ * C_ * HW_;
    unsigned short* w16p = w16q + 768 * 256;
    unsigned short* qT   = w16p + 256 * 256;
    unsigned short* kT   = qT + (size_t)B_ * NH_ * HW_ * 64;
    unsigned short* vN   = kT + (size_t)B_ * NH_ * HW_ * 64;
    unsigned short* OP   = vN + (size_t)B_ * C_ * HW_;
    float*          LP   = (float*)(OP + (size_t)2 * B_ * C_ * HW_);
    (void)in_sizes; (void)n_in; (void)out_size; (void)ws_size;

    gn_wcvt_kernel<<<dim3(768), 256, 0, stream>>>(
        x, gn_w, gn_b, y16, qkv_w, proj_w, w16q, w16p);

    qkv_mfma_kernel<<<dim3(HW_ / 64, 3, B_), 256, 0, stream>>>(
        w16q, y16, qkv_b, qT, kT, vN);

    attn_mfma_kernel<<<dim3(NH_ * B_, HW_ / 128, 2), 256, 0, stream>>>(qT, kT, vN, OP, LP);

    proj_mfma_kernel<<<dim3(HW_ / 64, C_ / 64, B_), 256, 0, stream>>>(
        w16p, OP, LP, proj_b, x, out);
}

// Round 15
// 147.598 us; speedup vs baseline: 1.2141x; 1.2141x over previous
//
#include <hip/hip_runtime.h>
#include <cstddef>

// ---- problem constants ----
#define B_   16
#define C_   256
#define HW_  1024
#define NH_  4
#define NG_  32
#define CPG_ 8          // channels per group
#define CS_  0.18033688f   // 0.125 * log2(e), folded into Q at QKV epilogue

typedef __attribute__((ext_vector_type(8))) short bf16x8;
typedef __attribute__((ext_vector_type(4))) short s16x4;
typedef __attribute__((ext_vector_type(8))) _Float16 f16x8;
typedef __attribute__((ext_vector_type(4))) float f32x4;

#define MFMA16B(a, b, c) __builtin_amdgcn_mfma_f32_16x16x32_bf16(a, b, c, 0, 0, 0)
#define MFMA16H(a, b, c) __builtin_amdgcn_mfma_f32_16x16x32_f16(a, b, c, 0, 0, 0)

#if __has_builtin(__builtin_amdgcn_mfma_f32_16x16x16bf16_1k)
#define HAVE_MFMA16K16 1
#define MFMA16B4(a, b, c) __builtin_amdgcn_mfma_f32_16x16x16bf16_1k(a, b, c, 0, 0, 0)
#else
#define HAVE_MFMA16K16 0
#endif

// ---- bf16 <-> f32 helpers ----
__device__ __forceinline__ float bf2f(unsigned short h) {
    unsigned int u = ((unsigned int)h) << 16;
    return __builtin_bit_cast(float, u);
}
__device__ __forceinline__ unsigned short f2bf(float f) {
    unsigned int u = __builtin_bit_cast(unsigned int, f);
    u += 0x7FFFu + ((u >> 16) & 1u);   // round-to-nearest-even
    return (unsigned short)(u >> 16);
}
#if __has_builtin(__builtin_amdgcn_cvt_pk_bf16_f32)
__device__ __forceinline__ unsigned packbf(float a, float b) {
    auto v = __builtin_amdgcn_cvt_pk_bf16_f32(a, b);   // lo=a, hi=b
    return __builtin_bit_cast(unsigned, v);
}
#else
__device__ __forceinline__ unsigned packbf(float a, float b) {
    unsigned ua = __builtin_bit_cast(unsigned, a) + 0x8000u;
    unsigned ub = __builtin_bit_cast(unsigned, b) + 0x8000u;
    return __builtin_amdgcn_perm(ub, ua, 0x07060302u);
}
#endif
__device__ __forceinline__ unsigned pkh(float a, float b) {
    auto h2 = __builtin_amdgcn_cvt_pkrtz(a, b);   // __fp16 ext_vector(2)
    return __builtin_bit_cast(unsigned, h2);
}

// =====================================================================
// Fused GN-apply + weight-convert.
// Blocks 0..511: GroupNorm (b,g): stats, then write y16 = f16(GN(x)).
// Blocks 512..767: fp32->f16 weight conversion.
// =====================================================================
__global__ __launch_bounds__(256) void gn_wcvt_kernel(
    const float* __restrict__ x,
    const float* __restrict__ gw,
    const float* __restrict__ gb,
    unsigned short* __restrict__ y16,       // f16 [B*C*HW]
    const float* __restrict__ qw, const float* __restrict__ pw,
    unsigned short* __restrict__ oq, unsigned short* __restrict__ op)
{
    if (blockIdx.x >= 512) {
        int i = (blockIdx.x - 512) * 256 + threadIdx.x;   // 65536 float4s
        const float* s; unsigned short* d; int j;
        if (i < 49152) { s = qw; d = oq; j = i; }
        else           { s = pw; d = op; j = i - 49152; }
        float4 f = ((const float4*)s)[j];
        uint2 u = {pkh(f.x, f.y), pkh(f.z, f.w)};
        *(uint2*)&d[(size_t)j * 4] = u;
        return;
    }
    int blk = blockIdx.x;                 // b*NG + g
    const size_t base = (size_t)blk * CPG_ * HW_;
    const float* xg = x + base;
    const int N = CPG_ * HW_;             // 8192

    float s = 0.f, ss = 0.f;
    for (int e = threadIdx.x * 4; e < N; e += 1024) {
        float4 v4 = *(const float4*)&xg[e];
        s  += v4.x + v4.y + v4.z + v4.w;
        ss += v4.x * v4.x + v4.y * v4.y + v4.z * v4.z + v4.w * v4.w;
    }
    #pragma unroll
    for (int off = 32; off > 0; off >>= 1) {
        s  += __shfl_down(s, off, 64);
        ss += __shfl_down(ss, off, 64);
    }
    __shared__ float red[8];
    __shared__ float2 stf;
    int lane = threadIdx.x & 63, wv = threadIdx.x >> 6;
    if (lane == 0) { red[wv] = s; red[4 + wv] = ss; }
    __syncthreads();
    if (threadIdx.x == 0) {
        float S  = red[0] + red[1] + red[2] + red[3];
        float SS = red[4] + red[5] + red[6] + red[7];
        float mean = S / (float)N;
        float var  = SS / (float)N - mean * mean;
        stf = make_float2(mean, rsqrtf(var + 1e-5f));
    }
    __syncthreads();
    float mean = stf.x, rstd = stf.y;
    for (int e = threadIdx.x * 4; e < N; e += 1024) {
        int ch = (blk & 31) * CPG_ + (e >> 10);
        float sc = rstd * gw[ch];
        float sh = gb[ch] - mean * sc;
        float4 v4 = *(const float4*)&xg[e];
        uint2 u;
        u.x = pkh(v4.x * sc + sh, v4.y * sc + sh);
        u.y = pkh(v4.z * sc + sh, v4.w * sc + sh);
        *(uint2*)&y16[base + e] = u;
    }
}

// =====================================================================
// QKV MFMA GEMM R15 (f16, fp32 accum): R13's proven 128m x 64n x 32k
// tile (grid 1536 = ~6 blocks/CU pressure, 4 resident at 36.9KB LDS),
// dbuf LDS + register prefetch, one barrier per K-step; B-stage reads
// pre-normalized y16 -> pure bit-pack (no GN math, no scsh loads).
// Epilogue -> qT/kT (Q scaled CS_) or vN.
// =====================================================================
__global__ __launch_bounds__(256) void qkv_mfma_kernel(
    const unsigned short* __restrict__ W16,
    const unsigned short* __restrict__ y16,  // f16 [B*256][1024]
    const float* __restrict__ bias,
    unsigned short* __restrict__ qT,   // bf16 [B*4][1024][64]
    unsigned short* __restrict__ kT,   // bf16 [B*4][1024][64]
    unsigned short* __restrict__ vN)   // bf16 [B*256][1024]
{
    const int K = 256, N = 1024;
    __shared__ union {
        struct { unsigned short A[2][128][40]; unsigned short Bt[2][64][40]; } st;
        unsigned short nd[2][64][72];   // Q/K epilogue: [half][n][d]
        unsigned short mn[128][72];     // V epilogue:   [m][n]
    } L;

    const int b  = blockIdx.z;
    const int m0 = blockIdx.y * 128, n0 = blockIdx.x * 64;
    const int t  = threadIdx.x;
    const int l15 = t & 15, quad = (t >> 4) & 3;
    const int wave = t >> 6, wm = wave >> 1, wn = wave & 1;

    union HF { uint4 q; f16x8 v; };

    f32x4 acc[4][2];
    #pragma unroll
    for (int mt = 0; mt < 4; ++mt)
        #pragma unroll
        for (int nt = 0; nt < 2; ++nt)
            acc[mt][nt] = (f32x4){0.f, 0.f, 0.f, 0.f};

    const int ar = t >> 1, akh = (t & 1) * 16;     // A: row, k-half
    const int bn = t & 63, bkb = t >> 6;           // B: n, k-block(8)

    uint4 pa0, pa1;            // A prefetch
    unsigned short ph[8];      // B prefetch: 8 k of column n0+bn

    auto PREF = [&](int k0) {
        const unsigned short* wp = &W16[(size_t)(m0 + ar) * K + k0 + akh];
        pa0 = *(const uint4*)wp;
        pa1 = *(const uint4*)(wp + 8);
        int ch = k0 + bkb * 8;
        const unsigned short* xp = &y16[((size_t)b * 256 + ch) * 1024 + n0 + bn];
        #pragma unroll
        for (int j = 0; j < 8; ++j) ph[j] = xp[(size_t)j * 1024];
    };

    PREF(0);
    #pragma unroll 1
    for (int it = 0; it < 8; ++it) {
        const int bsel = it & 1;
        *(uint4*)&L.st.A[bsel][ar][akh]     = pa0;
        *(uint4*)&L.st.A[bsel][ar][akh + 8] = pa1;
        {
            uint4 bw;
            bw.x = (unsigned)ph[0] | ((unsigned)ph[1] << 16);
            bw.y = (unsigned)ph[2] | ((unsigned)ph[3] << 16);
            bw.z = (unsigned)ph[4] | ((unsigned)ph[5] << 16);
            bw.w = (unsigned)ph[6] | ((unsigned)ph[7] << 16);
            *(uint4*)&L.st.Bt[bsel][bn][bkb * 8] = bw;
        }
        __syncthreads();
        if (it + 1 < 8) PREF((it + 1) * 32);
        HF af[4], bfv[2];
        #pragma unroll
        for (int mt = 0; mt < 4; ++mt)
            af[mt].q = *(const uint4*)&L.st.A[bsel][wm * 64 + mt * 16 + l15][quad * 8];
        #pragma unroll
        for (int nt = 0; nt < 2; ++nt)
            bfv[nt].q = *(const uint4*)&L.st.Bt[bsel][wn * 32 + nt * 16 + l15][quad * 8];
        #pragma unroll
        for (int mt = 0; mt < 4; ++mt)
            #pragma unroll
            for (int nt = 0; nt < 2; ++nt)
                acc[mt][nt] = MFMA16H(af[mt].v, bfv[nt].v, acc[mt][nt]);
    }
    __syncthreads();   // LDS union reused by epilogue

    if (m0 < 512) {
        // Q/K epilogue; Q region pre-scaled by CS_ for exp2-domain softmax
        const float qsc = (m0 < 256) ? CS_ : 1.f;
        #pragma unroll
        for (int mt = 0; mt < 4; ++mt)
            #pragma unroll
            for (int rr = 0; rr < 4; ++rr) {
                int dl = mt * 16 + quad * 4 + rr;
                float bv = bias[m0 + wm * 64 + dl];
                #pragma unroll
                for (int nt = 0; nt < 2; ++nt)
                    L.nd[wm][wn * 32 + nt * 16 + l15][dl] = f2bf((acc[mt][nt][rr] + bv) * qsc);
            }
        __syncthreads();
        unsigned short* dst = (m0 < 256) ? qT : kT;
        int headbase = (m0 & 255) >> 6;
        int hl = t >> 7, tt = t & 127;
        int nl = tt >> 1, db = (tt & 1) * 32;
        const unsigned short* src = &L.nd[hl][nl][db];
        unsigned short* gp = &dst[(((size_t)(b * 4 + headbase + hl)) * 1024 + n0 + nl) * 64 + db];
        uint4 u0 = *(const uint4*)(src);
        uint4 u1 = *(const uint4*)(src + 8);
        uint4 u2 = *(const uint4*)(src + 16);
        uint4 u3 = *(const uint4*)(src + 24);
        *(uint4*)(gp)      = u0;
        *(uint4*)(gp + 8)  = u1;
        *(uint4*)(gp + 16) = u2;
        *(uint4*)(gp + 24) = u3;
    } else {
        #pragma unroll
        for (int mt = 0; mt < 4; ++mt)
            #pragma unroll
            for (int rr = 0; rr < 4; ++rr) {
                int ml = wm * 64 + mt * 16 + quad * 4 + rr;
                float bv = bias[m0 + ml];
                #pragma unroll
                for (int nt = 0; nt < 2; ++nt)
                    L.mn[ml][wn * 32 + nt * 16 + l15] = f2bf(acc[mt][nt][rr] + bv);
            }
        __syncthreads();
        int ml = t & 127, nb = t >> 7;
        const unsigned short* src = &L.mn[ml][nb * 32];
        unsigned short* gp = &vN[((size_t)b * 256 + (m0 - 512) + ml) * 1024 + n0 + nb * 32];
        uint4 u0 = *(const uint4*)(src);
        uint4 u1 = *(const uint4*)(src + 8);
        uint4 u2 = *(const uint4*)(src + 16);
        uint4 u3 = *(const uint4*)(src + 24);
        *(uint4*)(gp)      = u0;
        *(uint4*)(gp + 8)  = u1;
        *(uint4*)(gp + 16) = u2;
        *(uint4*)(gp + 24) = u3;
    }
}

// =====================================================================
// Proj MFMA GEMM (R13): tile 64m x 64n x 32k, grid 1024 (4 blocks/CU).
// B-stage fuses attention combine: (OP0+OP1) * 1/(l0+l1).
// out = fp32 d_out + bias + residual.
// =====================================================================
__global__ __launch_bounds__(256) void proj_mfma_kernel(
    const unsigned short* __restrict__ W16,
    const unsigned short* __restrict__ OP,   // bf16 [2][64][64][1024]
    const float* __restrict__ LPp,           // fp32 [2][64][1024]
    const float* __restrict__ bias,
    const float* __restrict__ res,
    float* __restrict__ outF)
{
    const int M = 256, K = 256, N = 1024;
    __shared__ struct { unsigned short A[2][64][40]; unsigned short Bt[2][64][40]; } L;

    const int b  = blockIdx.z;
    const int m0 = blockIdx.y * 64, n0 = blockIdx.x * 64;
    const int t  = threadIdx.x;
    const int l15 = t & 15, quad = (t >> 4) & 3;
    const int wave = t >> 6, wm = wave >> 1, wn = wave & 1;

    union HF { uint4 q; f16x8 v; };

    f32x4 acc[2][2];
    #pragma unroll
    for (int mt = 0; mt < 2; ++mt)
        #pragma unroll
        for (int nt = 0; nt < 2; ++nt)
            acc[mt][nt] = (f32x4){0.f, 0.f, 0.f, 0.f};

    const int ar = t >> 2, akh = (t & 3) * 8;      // A: 64 rows, 8 f16 each
    const int bn = t & 63, bkb = t >> 6;           // B: n, k-block(8)

    float rinv[4];
    {
        int n = n0 + bn;
        #pragma unroll
        for (int h = 0; h < 4; ++h) {
            float l0 = LPp[(size_t)(b * 4 + h) * 1024 + n];
            float l1 = LPp[(size_t)(64 + b * 4 + h) * 1024 + n];
            rinv[h] = 1.f / (l0 + l1);
        }
    }

    uint4 pa;
    unsigned short ph0[8], ph1[8];
    int pH = 0;

    auto PREF = [&](int k0) {
        pa = *(const uint4*)&W16[(size_t)(m0 + ar) * K + k0 + akh];
        int ch = k0 + bkb * 8;
        pH = ch >> 6;
        size_t base = ((size_t)(b * 4 + pH) * 64 + (ch & 63)) * 1024 + n0 + bn;
        #pragma unroll
        for (int j = 0; j < 8; ++j) {
            ph0[j] = OP[base + (size_t)j * 1024];
            ph1[j] = OP[(size_t)64 * 64 * 1024 + base + (size_t)j * 1024];
        }
    };

    PREF(0);
    #pragma unroll 1
    for (int it = 0; it < 8; ++it) {
        const int bsel = it & 1;
        *(uint4*)&L.A[bsel][ar][akh] = pa;
        {
            float ri = rinv[pH];
            float v[8];
            #pragma unroll
            for (int j = 0; j < 8; ++j)
                v[j] = (bf2f(ph0[j]) + bf2f(ph1[j])) * ri;
            uint4 bw = {pkh(v[0], v[1]), pkh(v[2], v[3]), pkh(v[4], v[5]), pkh(v[6], v[7])};
            *(uint4*)&L.Bt[bsel][bn][bkb * 8] = bw;
        }
        __syncthreads();
        if (it + 1 < 8) PREF((it + 1) * 32);
        HF af[2], bfv[2];
        #pragma unroll
        for (int mt = 0; mt < 2; ++mt)
            af[mt].q = *(const uint4*)&L.A[bsel][wm * 32 + mt * 16 + l15][quad * 8];
        #pragma unroll
        for (int nt = 0; nt < 2; ++nt)
            bfv[nt].q = *(const uint4*)&L.Bt[bsel][wn * 32 + nt * 16 + l15][quad * 8];
        #pragma unroll
        for (int mt = 0; mt < 2; ++mt)
            #pragma unroll
            for (int nt = 0; nt < 2; ++nt)
                acc[mt][nt] = MFMA16H(af[mt].v, bfv[nt].v, acc[mt][nt]);
    }

    #pragma unroll
    for (int mt = 0; mt < 2; ++mt) {
        #pragma unroll
        for (int rr = 0; rr < 4; ++rr) {
            int m = m0 + wm * 32 + mt * 16 + quad * 4 + rr;
            float bv = bias[m];
            #pragma unroll
            for (int nt = 0; nt < 2; ++nt) {
                int n = n0 + wn * 32 + nt * 16 + l15;
                size_t off = ((size_t)b * M + m) * (size_t)N + n;
                outF[off] = acc[mt][nt][rr] + bv + res[off];
            }
        }
    }
}

// =====================================================================
// MFMA flash attention (R12 structure, unchanged): 128-q blocks, jh=2
// split, dbuf LDS, one barrier/iter, register prefetch. PV via x16
// MFMA (C-layout pack == x16 B-frag, no shuffles); l via ones-row MFMA.
// =====================================================================
__global__ __launch_bounds__(256) void attn_mfma_kernel(
    const unsigned short* __restrict__ qT,
    const unsigned short* __restrict__ kT,
    const unsigned short* __restrict__ vN,
    unsigned short* __restrict__ OP,   // [2][64][64][1024] bf16 unnormalized
    float* __restrict__ LP)            // [2][64][1024] fp32 partial l
{
    __shared__ unsigned short Kt[2][64][72];   // [buf][kv][d]
    __shared__ unsigned short Vs[2][64][72];   // [buf][d][kv]

    const int t    = threadIdx.x;
    const int wv   = t >> 6;
    const int l15  = t & 15;
    const int quad = (t >> 4) & 3;
    const int bh   = blockIdx.x;            // b*4 + h
    const int i0   = blockIdx.y * 128;
    const int jh   = blockIdx.z;            // kv half

    union FragU { uint4 q; unsigned u[4]; bf16x8 v; };

    FragU qf[2][2];
    {
        const unsigned short* qg = qT + (size_t)bh * (1024 * 64);
        int qrow = i0 + wv * 32 + l15;
        #pragma unroll
        for (int nt = 0; nt < 2; ++nt)
            #pragma unroll
            for (int kt = 0; kt < 2; ++kt)
                qf[nt][kt].q = *(const uint4*)&qg[(size_t)(qrow + nt * 16) * 64 + kt * 32 + quad * 8];
    }

    f32x4 accO[4][2];
    #pragma unroll
    for (int m = 0; m < 4; ++m)
        #pragma unroll
        for (int n = 0; n < 2; ++n)
            accO[m][n] = (f32x4){0.f, 0.f, 0.f, 0.f};
    float l_i[2] = {0.f, 0.f};
#if HAVE_MFMA16K16
    f32x4 accL[2] = {(f32x4){0.f, 0.f, 0.f, 0.f}, (f32x4){0.f, 0.f, 0.f, 0.f}};
    const s16x4 ones4 = {(short)0x3F80, (short)0x3F80, (short)0x3F80, (short)0x3F80};
#endif

    const unsigned short* kg = kT + (size_t)bh * (1024 * 64);
    const unsigned short* vg = vN + (size_t)bh * (64 * 1024);

    const int slbase = l15 + ((quad & 1) << 5);
    const bool upper = (t & 32) != 0;
    (void)slbase; (void)upper;
    const int sr = t >> 2, sc = (t & 3) * 16;

    uint4 kr0, kr1, vr0, vr1;
    {
        const int j0 = jh * 512;
        const unsigned short* kp = &kg[(size_t)(j0 + sr) * 64 + sc];
        const unsigned short* vp = &vg[(size_t)sr * 1024 + j0 + sc];
        kr0 = *(const uint4*)kp;  kr1 = *(const uint4*)(kp + 8);
        vr0 = *(const uint4*)vp;  vr1 = *(const uint4*)(vp + 8);
    }

    for (int it = 0; it < 8; ++it) {
        const int bsel = it & 1;
        *(uint4*)&Kt[bsel][sr][sc]     = kr0;
        *(uint4*)&Kt[bsel][sr][sc + 8] = kr1;
        *(uint4*)&Vs[bsel][sr][sc]     = vr0;
        *(uint4*)&Vs[bsel][sr][sc + 8] = vr1;
        __syncthreads();
        if (it < 7) {
            const int j0n = jh * 512 + (it + 1) * 64;
            const unsigned short* kp = &kg[(size_t)(j0n + sr) * 64 + sc];
            const unsigned short* vp = &vg[(size_t)sr * 1024 + j0n + sc];
            kr0 = *(const uint4*)kp;  kr1 = *(const uint4*)(kp + 8);
            vr0 = *(const uint4*)vp;  vr1 = *(const uint4*)(vp + 8);
        }

        // ---- S^T = K · Q^T ----
        f32x4 accS[4][2];
        #pragma unroll
        for (int mt = 0; mt < 4; ++mt) {
            FragU ak[2];
            #pragma unroll
            for (int kt = 0; kt < 2; ++kt)
                ak[kt].q = *(const uint4*)&Kt[bsel][mt * 16 + l15][kt * 32 + quad * 8];
            #pragma unroll
            for (int nt = 0; nt < 2; ++nt) {
                f32x4 z = (f32x4){0.f, 0.f, 0.f, 0.f};
                z = MFMA16B(ak[0].v, qf[nt][0].v, z);
                z = MFMA16B(ak[1].v, qf[nt][1].v, z);
                accS[mt][nt] = z;
            }
        }

#if HAVE_MFMA16K16
        union PB { unsigned u[2]; s16x4 v; };
        PB pb[4][2];
        #pragma unroll
        for (int mt = 0; mt < 4; ++mt)
            #pragma unroll
            for (int nt = 0; nt < 2; ++nt) {
                float p0 = exp2f(accS[mt][nt][0]);
                float p1 = exp2f(accS[mt][nt][1]);
                float p2 = exp2f(accS[mt][nt][2]);
                float p3 = exp2f(accS[mt][nt][3]);
                pb[mt][nt].u[0] = packbf(p0, p1);
                pb[mt][nt].u[1] = packbf(p2, p3);
            }
        #pragma unroll
        for (int mt = 0; mt < 4; ++mt)
            #pragma unroll
            for (int nt = 0; nt < 2; ++nt)
                accL[nt] = MFMA16B4(ones4, pb[mt][nt].v, accL[nt]);
        #pragma unroll
        for (int mtd = 0; mtd < 4; ++mtd) {
            union AV { uint2 d; s16x4 v; } av[4];
            #pragma unroll
            for (int mt = 0; mt < 4; ++mt)
                av[mt].d = *(const uint2*)&Vs[bsel][mtd * 16 + l15][mt * 16 + quad * 4];
            #pragma unroll
            for (int nt = 0; nt < 2; ++nt)
                #pragma unroll
                for (int mt = 0; mt < 4; ++mt)
                    accO[mtd][nt] = MFMA16B4(av[mt].v, pb[mt][nt].v, accO[mtd][nt]);
        }
#else
        float rs[2] = {0.f, 0.f};
        unsigned pk[4][2][2];
        #pragma unroll
        for (int mt = 0; mt < 4; ++mt)
            #pragma unroll
            for (int nt = 0; nt < 2; ++nt) {
                float p0 = exp2f(accS[mt][nt][0]);
                float p1 = exp2f(accS[mt][nt][1]);
                float p2 = exp2f(accS[mt][nt][2]);
                float p3 = exp2f(accS[mt][nt][3]);
                rs[nt] += (p0 + p1) + (p2 + p3);
                pk[mt][nt][0] = packbf(p0, p1);
                pk[mt][nt][1] = packbf(p2, p3);
            }
        #pragma unroll
        for (int nt = 0; nt < 2; ++nt) {
            float r = rs[nt];
            r += __shfl_xor(r, 16, 64);
            r += __shfl_xor(r, 32, 64);
            l_i[nt] += r;
        }
        FragU bfr[2][2];
        #pragma unroll
        for (int kt = 0; kt < 2; ++kt)
            #pragma unroll
            for (int nt = 0; nt < 2; ++nt)
                #pragma unroll
                for (int w4 = 0; w4 < 4; ++w4) {
                    int sl = slbase + ((w4 >> 1) << 4);
                    int lo = __shfl((int)pk[2 * kt + 0][nt][w4 & 1], sl, 64);
                    int hi = __shfl((int)pk[2 * kt + 1][nt][w4 & 1], sl, 64);
                    bfr[kt][nt].u[w4] = (unsigned)(upper ? hi : lo);
                }
        #pragma unroll
        for (int mtd = 0; mtd < 4; ++mtd) {
            FragU av[2];
            #pragma unroll
            for (int kt = 0; kt < 2; ++kt)
                av[kt].q = *(const uint4*)&Vs[bsel][mtd * 16 + l15][kt * 32 + quad * 8];
            #pragma unroll
            for (int nt = 0; nt < 2; ++nt) {
                accO[mtd][nt] = MFMA16B(av[0].v, bfr[0][nt].v, accO[mtd][nt]);
                accO[mtd][nt] = MFMA16B(av[1].v, bfr[1][nt].v, accO[mtd][nt]);
            }
        }
#endif
    }

#if HAVE_MFMA16K16
    l_i[0] = accL[0][0];
    l_i[1] = accL[1][0];
#endif

    unsigned short* ob = OP + ((size_t)jh * 64 + bh) * (64 * 1024) + i0 + wv * 32;
    #pragma unroll
    for (int mtd = 0; mtd < 4; ++mtd)
        #pragma unroll
        for (int nt = 0; nt < 2; ++nt)
            #pragma unroll
            for (int rr = 0; rr < 4; ++rr) {
                int d = mtd * 16 + quad * 4 + rr;
                ob[(size_t)d * 1024 + nt * 16 + l15] = f2bf(accO[mtd][nt][rr]);
            }
    if (quad == 0) {
        float* lp = &LP[((size_t)jh * 64 + bh) * 1024 + i0 + wv * 32 + l15];
        lp[0]  = l_i[0];
        lp[16] = l_i[1];
    }
}

// =====================================================================
extern "C" void kernel_launch(void* const* d_in, const int* in_sizes, int n_in,
                              void* d_out, int out_size, void* d_ws, size_t ws_size,
                              hipStream_t stream)
{
    const float* x      = (const float*)d_in[0];
    const float* gn_w   = (const float*)d_in[1];
    const float* gn_b   = (const float*)d_in[2];
    const float* qkv_w  = (const float*)d_in[3];
    const float* qkv_b  = (const float*)d_in[4];
    const float* proj_w = (const float*)d_in[5];
    const float* proj_b = (const float*)d_in[6];
    float* out = (float*)d_out;

    // ws: y16 8.4MB | w16q 384KB | w16p 128KB | qT/kT/vN 8MB each |
    //     OP 16.8MB | LP 512KB   (~50 MB total)
    char* ws = (char*)d_ws;
    unsigned short* y16  = (unsigned short*)ws;
    unsigned short* w16q = y16 + (size_t)B_ * C_ * HW_;
    unsigned short* w16p = w16q + 768 * 256;
    unsigned short* qT   = w16p + 256 * 256;
    unsigned short* kT   = qT + (size_t)B_ * NH_ * HW_ * 64;
    unsigned short* vN   = kT + (size_t)B_ * NH_ * HW_ * 64;
    unsigned short* OP   = vN + (size_t)B_ * C_ * HW_;
    float*          LP   = (float*)(OP + (size_t)2 * B_ * C_ * HW_);
    (void)in_sizes; (void)n_in; (void)out_size; (void)ws_size;

    gn_wcvt_kernel<<<dim3(768), 256, 0, stream>>>(
        x, gn_w, gn_b, y16, qkv_w, proj_w, w16q, w16p);

    qkv_mfma_kernel<<<dim3(HW_ / 64, 6, B_), 256, 0, stream>>>(
        w16q, y16, qkv_b, qT, kT, vN);

    attn_mfma_kernel<<<dim3(NH_ * B_, HW_ / 128, 2), 256, 0, stream>>>(qT, kT, vN, OP, LP);

    proj_mfma_kernel<<<dim3(HW_ / 64, C_ / 64, B_), 256, 0, stream>>>(
        w16p, OP, LP, proj_b, x, out);
}

// Round 16
// 147.383 us; speedup vs baseline: 1.2159x; 1.0015x over previous
//
#include <hip/hip_runtime.h>
#include <cstddef>

// ---- problem constants ----
#define B_   16
#define C_   256
#define HW_  1024
#define NH_  4
#define NG_  32
#define CPG_ 8          // channels per group
#define CS_  0.18033688f   // 0.125 * log2(e), folded into Q at QKV epilogue

typedef __attribute__((ext_vector_type(8))) short bf16x8;
typedef __attribute__((ext_vector_type(4))) short s16x4;
typedef __attribute__((ext_vector_type(8))) _Float16 f16x8;
typedef __attribute__((ext_vector_type(4))) float f32x4;

#define MFMA16B(a, b, c) __builtin_amdgcn_mfma_f32_16x16x32_bf16(a, b, c, 0, 0, 0)
#define MFMA16H(a, b, c) __builtin_amdgcn_mfma_f32_16x16x32_f16(a, b, c, 0, 0, 0)

#if __has_builtin(__builtin_amdgcn_mfma_f32_16x16x16bf16_1k)
#define HAVE_MFMA16K16 1
#define MFMA16B4(a, b, c) __builtin_amdgcn_mfma_f32_16x16x16bf16_1k(a, b, c, 0, 0, 0)
#else
#define HAVE_MFMA16K16 0
#endif

// ---- bf16 <-> f32 helpers ----
__device__ __forceinline__ float bf2f(unsigned short h) {
    unsigned int u = ((unsigned int)h) << 16;
    return __builtin_bit_cast(float, u);
}
__device__ __forceinline__ unsigned short f2bf(float f) {
    unsigned int u = __builtin_bit_cast(unsigned int, f);
    u += 0x7FFFu + ((u >> 16) & 1u);   // round-to-nearest-even
    return (unsigned short)(u >> 16);
}
#if __has_builtin(__builtin_amdgcn_cvt_pk_bf16_f32)
__device__ __forceinline__ unsigned packbf(float a, float b) {
    auto v = __builtin_amdgcn_cvt_pk_bf16_f32(a, b);   // lo=a, hi=b
    return __builtin_bit_cast(unsigned, v);
}
#else
__device__ __forceinline__ unsigned packbf(float a, float b) {
    unsigned ua = __builtin_bit_cast(unsigned, a) + 0x8000u;
    unsigned ub = __builtin_bit_cast(unsigned, b) + 0x8000u;
    return __builtin_amdgcn_perm(ub, ua, 0x07060302u);
}
#endif
__device__ __forceinline__ unsigned pkh(float a, float b) {
    auto h2 = __builtin_amdgcn_cvt_pkrtz(a, b);   // __fp16 ext_vector(2)
    return __builtin_bit_cast(unsigned, h2);
}

// =====================================================================
// Fused GN-apply + weight-convert.
// Blocks 0..511: GroupNorm (b,g): stats, then write y16 = f16(GN(x)).
// Blocks 512..767: fp32->f16 weight conversion.
// =====================================================================
__global__ __launch_bounds__(256) void gn_wcvt_kernel(
    const float* __restrict__ x,
    const float* __restrict__ gw,
    const float* __restrict__ gb,
    unsigned short* __restrict__ y16,       // f16 [B*C*HW]
    const float* __restrict__ qw, const float* __restrict__ pw,
    unsigned short* __restrict__ oq, unsigned short* __restrict__ op)
{
    if (blockIdx.x >= 512) {
        int i = (blockIdx.x - 512) * 256 + threadIdx.x;   // 65536 float4s
        const float* s; unsigned short* d; int j;
        if (i < 49152) { s = qw; d = oq; j = i; }
        else           { s = pw; d = op; j = i - 49152; }
        float4 f = ((const float4*)s)[j];
        uint2 u = {pkh(f.x, f.y), pkh(f.z, f.w)};
        *(uint2*)&d[(size_t)j * 4] = u;
        return;
    }
    int blk = blockIdx.x;                 // b*NG + g
    const size_t base = (size_t)blk * CPG_ * HW_;
    const float* xg = x + base;
    const int N = CPG_ * HW_;             // 8192

    float s = 0.f, ss = 0.f;
    for (int e = threadIdx.x * 4; e < N; e += 1024) {
        float4 v4 = *(const float4*)&xg[e];
        s  += v4.x + v4.y + v4.z + v4.w;
        ss += v4.x * v4.x + v4.y * v4.y + v4.z * v4.z + v4.w * v4.w;
    }
    #pragma unroll
    for (int off = 32; off > 0; off >>= 1) {
        s  += __shfl_down(s, off, 64);
        ss += __shfl_down(ss, off, 64);
    }
    __shared__ float red[8];
    __shared__ float2 stf;
    int lane = threadIdx.x & 63, wv = threadIdx.x >> 6;
    if (lane == 0) { red[wv] = s; red[4 + wv] = ss; }
    __syncthreads();
    if (threadIdx.x == 0) {
        float S  = red[0] + red[1] + red[2] + red[3];
        float SS = red[4] + red[5] + red[6] + red[7];
        float mean = S / (float)N;
        float var  = SS / (float)N - mean * mean;
        stf = make_float2(mean, rsqrtf(var + 1e-5f));
    }
    __syncthreads();
    float mean = stf.x, rstd = stf.y;
    for (int e = threadIdx.x * 4; e < N; e += 1024) {
        int ch = (blk & 31) * CPG_ + (e >> 10);
        float sc = rstd * gw[ch];
        float sh = gb[ch] - mean * sc;
        float4 v4 = *(const float4*)&xg[e];
        uint2 u;
        u.x = pkh(v4.x * sc + sh, v4.y * sc + sh);
        u.y = pkh(v4.z * sc + sh, v4.w * sc + sh);
        *(uint2*)&y16[base + e] = u;
    }
}

// =====================================================================
// QKV MFMA GEMM (R15, unchanged): 128m x 64n x 32k, dbuf LDS + register
// prefetch, one barrier per K-step; B-stage reads y16 -> pure bit-pack.
// =====================================================================
__global__ __launch_bounds__(256) void qkv_mfma_kernel(
    const unsigned short* __restrict__ W16,
    const unsigned short* __restrict__ y16,  // f16 [B*256][1024]
    const float* __restrict__ bias,
    unsigned short* __restrict__ qT,   // bf16 [B*4][1024][64]
    unsigned short* __restrict__ kT,   // bf16 [B*4][1024][64]
    unsigned short* __restrict__ vN)   // bf16 [B*256][1024]
{
    const int K = 256, N = 1024;
    __shared__ union {
        struct { unsigned short A[2][128][40]; unsigned short Bt[2][64][40]; } st;
        unsigned short nd[2][64][72];   // Q/K epilogue: [half][n][d]
        unsigned short mn[128][72];     // V epilogue:   [m][n]
    } L;

    const int b  = blockIdx.z;
    const int m0 = blockIdx.y * 128, n0 = blockIdx.x * 64;
    const int t  = threadIdx.x;
    const int l15 = t & 15, quad = (t >> 4) & 3;
    const int wave = t >> 6, wm = wave >> 1, wn = wave & 1;

    union HF { uint4 q; f16x8 v; };

    f32x4 acc[4][2];
    #pragma unroll
    for (int mt = 0; mt < 4; ++mt)
        #pragma unroll
        for (int nt = 0; nt < 2; ++nt)
            acc[mt][nt] = (f32x4){0.f, 0.f, 0.f, 0.f};

    const int ar = t >> 1, akh = (t & 1) * 16;     // A: row, k-half
    const int bn = t & 63, bkb = t >> 6;           // B: n, k-block(8)

    uint4 pa0, pa1;            // A prefetch
    unsigned short ph[8];      // B prefetch: 8 k of column n0+bn

    auto PREF = [&](int k0) {
        const unsigned short* wp = &W16[(size_t)(m0 + ar) * K + k0 + akh];
        pa0 = *(const uint4*)wp;
        pa1 = *(const uint4*)(wp + 8);
        int ch = k0 + bkb * 8;
        const unsigned short* xp = &y16[((size_t)b * 256 + ch) * 1024 + n0 + bn];
        #pragma unroll
        for (int j = 0; j < 8; ++j) ph[j] = xp[(size_t)j * 1024];
    };

    PREF(0);
    #pragma unroll 1
    for (int it = 0; it < 8; ++it) {
        const int bsel = it & 1;
        *(uint4*)&L.st.A[bsel][ar][akh]     = pa0;
        *(uint4*)&L.st.A[bsel][ar][akh + 8] = pa1;
        {
            uint4 bw;
            bw.x = (unsigned)ph[0] | ((unsigned)ph[1] << 16);
            bw.y = (unsigned)ph[2] | ((unsigned)ph[3] << 16);
            bw.z = (unsigned)ph[4] | ((unsigned)ph[5] << 16);
            bw.w = (unsigned)ph[6] | ((unsigned)ph[7] << 16);
            *(uint4*)&L.st.Bt[bsel][bn][bkb * 8] = bw;
        }
        __syncthreads();
        if (it + 1 < 8) PREF((it + 1) * 32);
        HF af[4], bfv[2];
        #pragma unroll
        for (int mt = 0; mt < 4; ++mt)
            af[mt].q = *(const uint4*)&L.st.A[bsel][wm * 64 + mt * 16 + l15][quad * 8];
        #pragma unroll
        for (int nt = 0; nt < 2; ++nt)
            bfv[nt].q = *(const uint4*)&L.st.Bt[bsel][wn * 32 + nt * 16 + l15][quad * 8];
        #pragma unroll
        for (int mt = 0; mt < 4; ++mt)
            #pragma unroll
            for (int nt = 0; nt < 2; ++nt)
                acc[mt][nt] = MFMA16H(af[mt].v, bfv[nt].v, acc[mt][nt]);
    }
    __syncthreads();   // LDS union reused by epilogue

    if (m0 < 512) {
        const float qsc = (m0 < 256) ? CS_ : 1.f;
        #pragma unroll
        for (int mt = 0; mt < 4; ++mt)
            #pragma unroll
            for (int rr = 0; rr < 4; ++rr) {
                int dl = mt * 16 + quad * 4 + rr;
                float bv = bias[m0 + wm * 64 + dl];
                #pragma unroll
                for (int nt = 0; nt < 2; ++nt)
                    L.nd[wm][wn * 32 + nt * 16 + l15][dl] = f2bf((acc[mt][nt][rr] + bv) * qsc);
            }
        __syncthreads();
        unsigned short* dst = (m0 < 256) ? qT : kT;
        int headbase = (m0 & 255) >> 6;
        int hl = t >> 7, tt = t & 127;
        int nl = tt >> 1, db = (tt & 1) * 32;
        const unsigned short* src = &L.nd[hl][nl][db];
        unsigned short* gp = &dst[(((size_t)(b * 4 + headbase + hl)) * 1024 + n0 + nl) * 64 + db];
        uint4 u0 = *(const uint4*)(src);
        uint4 u1 = *(const uint4*)(src + 8);
        uint4 u2 = *(const uint4*)(src + 16);
        uint4 u3 = *(const uint4*)(src + 24);
        *(uint4*)(gp)      = u0;
        *(uint4*)(gp + 8)  = u1;
        *(uint4*)(gp + 16) = u2;
        *(uint4*)(gp + 24) = u3;
    } else {
        #pragma unroll
        for (int mt = 0; mt < 4; ++mt)
            #pragma unroll
            for (int rr = 0; rr < 4; ++rr) {
                int ml = wm * 64 + mt * 16 + quad * 4 + rr;
                float bv = bias[m0 + ml];
                #pragma unroll
                for (int nt = 0; nt < 2; ++nt)
                    L.mn[ml][wn * 32 + nt * 16 + l15] = f2bf(acc[mt][nt][rr] + bv);
            }
        __syncthreads();
        int ml = t & 127, nb = t >> 7;
        const unsigned short* src = &L.mn[ml][nb * 32];
        unsigned short* gp = &vN[((size_t)b * 256 + (m0 - 512) + ml) * 1024 + n0 + nb * 32];
        uint4 u0 = *(const uint4*)(src);
        uint4 u1 = *(const uint4*)(src + 8);
        uint4 u2 = *(const uint4*)(src + 16);
        uint4 u3 = *(const uint4*)(src + 24);
        *(uint4*)(gp)      = u0;
        *(uint4*)(gp + 8)  = u1;
        *(uint4*)(gp + 16) = u2;
        *(uint4*)(gp + 24) = u3;
    }
}

// =====================================================================
// Proj MFMA GEMM (R13, unchanged): 64m x 64n x 32k, grid 1024.
// B-stage fuses attention combine: (OP0+OP1) * 1/(l0+l1).
// =====================================================================
__global__ __launch_bounds__(256) void proj_mfma_kernel(
    const unsigned short* __restrict__ W16,
    const unsigned short* __restrict__ OP,   // bf16 [2][64][64][1024]
    const float* __restrict__ LPp,           // fp32 [2][64][1024]
    const float* __restrict__ bias,
    const float* __restrict__ res,
    float* __restrict__ outF)
{
    const int M = 256, K = 256, N = 1024;
    __shared__ struct { unsigned short A[2][64][40]; unsigned short Bt[2][64][40]; } L;

    const int b  = blockIdx.z;
    const int m0 = blockIdx.y * 64, n0 = blockIdx.x * 64;
    const int t  = threadIdx.x;
    const int l15 = t & 15, quad = (t >> 4) & 3;
    const int wave = t >> 6, wm = wave >> 1, wn = wave & 1;

    union HF { uint4 q; f16x8 v; };

    f32x4 acc[2][2];
    #pragma unroll
    for (int mt = 0; mt < 2; ++mt)
        #pragma unroll
        for (int nt = 0; nt < 2; ++nt)
            acc[mt][nt] = (f32x4){0.f, 0.f, 0.f, 0.f};

    const int ar = t >> 2, akh = (t & 3) * 8;      // A: 64 rows, 8 f16 each
    const int bn = t & 63, bkb = t >> 6;           // B: n, k-block(8)

    float rinv[4];
    {
        int n = n0 + bn;
        #pragma unroll
        for (int h = 0; h < 4; ++h) {
            float l0 = LPp[(size_t)(b * 4 + h) * 1024 + n];
            float l1 = LPp[(size_t)(64 + b * 4 + h) * 1024 + n];
            rinv[h] = 1.f / (l0 + l1);
        }
    }

    uint4 pa;
    unsigned short ph0[8], ph1[8];
    int pH = 0;

    auto PREF = [&](int k0) {
        pa = *(const uint4*)&W16[(size_t)(m0 + ar) * K + k0 + akh];
        int ch = k0 + bkb * 8;
        pH = ch >> 6;
        size_t base = ((size_t)(b * 4 + pH) * 64 + (ch & 63)) * 1024 + n0 + bn;
        #pragma unroll
        for (int j = 0; j < 8; ++j) {
            ph0[j] = OP[base + (size_t)j * 1024];
            ph1[j] = OP[(size_t)64 * 64 * 1024 + base + (size_t)j * 1024];
        }
    };

    PREF(0);
    #pragma unroll 1
    for (int it = 0; it < 8; ++it) {
        const int bsel = it & 1;
        *(uint4*)&L.A[bsel][ar][akh] = pa;
        {
            float ri = rinv[pH];
            float v[8];
            #pragma unroll
            for (int j = 0; j < 8; ++j)
                v[j] = (bf2f(ph0[j]) + bf2f(ph1[j])) * ri;
            uint4 bw = {pkh(v[0], v[1]), pkh(v[2], v[3]), pkh(v[4], v[5]), pkh(v[6], v[7])};
            *(uint4*)&L.Bt[bsel][bn][bkb * 8] = bw;
        }
        __syncthreads();
        if (it + 1 < 8) PREF((it + 1) * 32);
        HF af[2], bfv[2];
        #pragma unroll
        for (int mt = 0; mt < 2; ++mt)
            af[mt].q = *(const uint4*)&L.A[bsel][wm * 32 + mt * 16 + l15][quad * 8];
        #pragma unroll
        for (int nt = 0; nt < 2; ++nt)
            bfv[nt].q = *(const uint4*)&L.Bt[bsel][wn * 32 + nt * 16 + l15][quad * 8];
        #pragma unroll
        for (int mt = 0; mt < 2; ++mt)
            #pragma unroll
            for (int nt = 0; nt < 2; ++nt)
                acc[mt][nt] = MFMA16H(af[mt].v, bfv[nt].v, acc[mt][nt]);
    }

    #pragma unroll
    for (int mt = 0; mt < 2; ++mt) {
        #pragma unroll
        for (int rr = 0; rr < 4; ++rr) {
            int m = m0 + wm * 32 + mt * 16 + quad * 4 + rr;
            float bv = bias[m];
            #pragma unroll
            for (int nt = 0; nt < 2; ++nt) {
                int n = n0 + wn * 32 + nt * 16 + l15;
                size_t off = ((size_t)b * M + m) * (size_t)N + n;
                outF[off] = acc[mt][nt][rr] + bv + res[off];
            }
        }
    }
}

// =====================================================================
// MFMA flash attention R16: 64-q blocks (small working set -> VGPR ~52,
// eligible for 8 waves/SIMD), jh=2 split, SINGLE-buffer LDS (18.4 KB ->
// 8 blocks/CU), two barriers/iter, register prefetch. PV via x16 MFMA
// (C-layout pack == x16 B-frag); l via ones-row MFMA.
// Grid (bh=64, qt=16, jh=2) = 2048 blocks.
// NO forced occupancy bound (R10 lesson).
// =====================================================================
__global__ __launch_bounds__(256) void attn_mfma_kernel(
    const unsigned short* __restrict__ qT,
    const unsigned short* __restrict__ kT,
    const unsigned short* __restrict__ vN,
    unsigned short* __restrict__ OP,   // [2][64][64][1024] bf16 unnormalized
    float* __restrict__ LP)            // [2][64][1024] fp32 partial l
{
    __shared__ unsigned short Kt[64][72];   // [kv][d]
    __shared__ unsigned short Vs[64][72];   // [d][kv]

    const int t    = threadIdx.x;
    const int wv   = t >> 6;
    const int l15  = t & 15;
    const int quad = (t >> 4) & 3;
    const int bh   = blockIdx.x;            // b*4 + h
    const int i0   = blockIdx.y * 64;
    const int jh   = blockIdx.z;            // kv half

    union FragU { uint4 q; unsigned u[4]; bf16x8 v; };

    // Q B-frags: 16 q cols per wave
    FragU qf[2];
    {
        const unsigned short* qg = qT + (size_t)bh * (1024 * 64);
        int qrow = i0 + wv * 16 + l15;
        #pragma unroll
        for (int kt = 0; kt < 2; ++kt)
            qf[kt].q = *(const uint4*)&qg[(size_t)qrow * 64 + kt * 32 + quad * 8];
    }

    f32x4 accO[4];
    #pragma unroll
    for (int m = 0; m < 4; ++m) accO[m] = (f32x4){0.f, 0.f, 0.f, 0.f};
    float l_i = 0.f;
#if HAVE_MFMA16K16
    f32x4 accL = (f32x4){0.f, 0.f, 0.f, 0.f};
    const s16x4 ones4 = {(short)0x3F80, (short)0x3F80, (short)0x3F80, (short)0x3F80};
#endif

    const unsigned short* kg = kT + (size_t)bh * (1024 * 64);
    const unsigned short* vg = vN + (size_t)bh * (64 * 1024);

    const int slbase = l15 + ((quad & 1) << 5);
    const bool upper = (t & 32) != 0;
    (void)slbase; (void)upper;
    const int sr = t >> 2, sc = (t & 3) * 16;   // staging: row 0..63, col 0/16/32/48

    uint4 kr0, kr1, vr0, vr1;
    {
        const int j0 = jh * 512;
        const unsigned short* kp = &kg[(size_t)(j0 + sr) * 64 + sc];
        const unsigned short* vp = &vg[(size_t)sr * 1024 + j0 + sc];
        kr0 = *(const uint4*)kp;  kr1 = *(const uint4*)(kp + 8);
        vr0 = *(const uint4*)vp;  vr1 = *(const uint4*)(vp + 8);
    }

    for (int it = 0; it < 8; ++it) {
        // ---- commit prefetched tile to LDS ----
        *(uint4*)&Kt[sr][sc]     = kr0;
        *(uint4*)&Kt[sr][sc + 8] = kr1;
        *(uint4*)&Vs[sr][sc]     = vr0;
        *(uint4*)&Vs[sr][sc + 8] = vr1;
        __syncthreads();
        // ---- issue prefetch of next tile (in flight during compute) ----
        if (it < 7) {
            const int j0n = jh * 512 + (it + 1) * 64;
            const unsigned short* kp = &kg[(size_t)(j0n + sr) * 64 + sc];
            const unsigned short* vp = &vg[(size_t)sr * 1024 + j0n + sc];
            kr0 = *(const uint4*)kp;  kr1 = *(const uint4*)(kp + 8);
            vr0 = *(const uint4*)vp;  vr1 = *(const uint4*)(vp + 8);
        }

        // ---- S^T = K · Q^T ----
        f32x4 accS[4];
        #pragma unroll
        for (int mt = 0; mt < 4; ++mt) {
            FragU ak[2];
            #pragma unroll
            for (int kt = 0; kt < 2; ++kt)
                ak[kt].q = *(const uint4*)&Kt[mt * 16 + l15][kt * 32 + quad * 8];
            f32x4 z = (f32x4){0.f, 0.f, 0.f, 0.f};
            z = MFMA16B(ak[0].v, qf[0].v, z);
            z = MFMA16B(ak[1].v, qf[1].v, z);
            accS[mt] = z;
        }

#if HAVE_MFMA16K16
        // ---- p = exp2(s); C-layout pack == x16 B-frag (no shuffles) ----
        union PB { unsigned u[2]; s16x4 v; };
        PB pb[4];
        #pragma unroll
        for (int mt = 0; mt < 4; ++mt) {
            float p0 = exp2f(accS[mt][0]);
            float p1 = exp2f(accS[mt][1]);
            float p2 = exp2f(accS[mt][2]);
            float p3 = exp2f(accS[mt][3]);
            pb[mt].u[0] = packbf(p0, p1);
            pb[mt].u[1] = packbf(p2, p3);
        }
        // ---- l[q] via ones-row MFMA ----
        #pragma unroll
        for (int mt = 0; mt < 4; ++mt)
            accL = MFMA16B4(ones4, pb[mt].v, accL);
        // ---- O^T += V^T · P^T  (x16 MFMA, A = V b64 frags) ----
        #pragma unroll
        for (int mtd = 0; mtd < 4; ++mtd) {
            union AV { uint2 d; s16x4 v; } av[4];
            #pragma unroll
            for (int mt = 0; mt < 4; ++mt)
                av[mt].d = *(const uint2*)&Vs[mtd * 16 + l15][mt * 16 + quad * 4];
            #pragma unroll
            for (int mt = 0; mt < 4; ++mt)
                accO[mtd] = MFMA16B4(av[mt].v, pb[mt].v, accO[mtd]);
        }
#else
        // ---- fallback: shuffle path ----
        float rs = 0.f;
        unsigned pk[4][2];
        #pragma unroll
        for (int mt = 0; mt < 4; ++mt) {
            float p0 = exp2f(accS[mt][0]);
            float p1 = exp2f(accS[mt][1]);
            float p2 = exp2f(accS[mt][2]);
            float p3 = exp2f(accS[mt][3]);
            rs += (p0 + p1) + (p2 + p3);
            pk[mt][0] = packbf(p0, p1);
            pk[mt][1] = packbf(p2, p3);
        }
        rs += __shfl_xor(rs, 16, 64);
        rs += __shfl_xor(rs, 32, 64);
        l_i += rs;
        FragU bfr[2];
        #pragma unroll
        for (int kt = 0; kt < 2; ++kt)
            #pragma unroll
            for (int w4 = 0; w4 < 4; ++w4) {
                int sl = slbase + ((w4 >> 1) << 4);
                int lo = __shfl((int)pk[2 * kt + 0][w4 & 1], sl, 64);
                int hi = __shfl((int)pk[2 * kt + 1][w4 & 1], sl, 64);
                bfr[kt].u[w4] = (unsigned)(upper ? hi : lo);
            }
        #pragma unroll
        for (int mtd = 0; mtd < 4; ++mtd) {
            FragU av[2];
            #pragma unroll
            for (int kt = 0; kt < 2; ++kt)
                av[kt].q = *(const uint4*)&Vs[mtd * 16 + l15][kt * 32 + quad * 8];
            accO[mtd] = MFMA16B(av[0].v, bfr[0].v, accO[mtd]);
            accO[mtd] = MFMA16B(av[1].v, bfr[1].v, accO[mtd]);
        }
#endif
        __syncthreads();   // all LDS reads done before next commit
    }

#if HAVE_MFMA16K16
    l_i = accL[0];
#endif

    // ---- epilogue: unnormalized O + partial l ----
    unsigned short* ob = OP + ((size_t)jh * 64 + bh) * (64 * 1024) + i0 + wv * 16;
    #pragma unroll
    for (int mtd = 0; mtd < 4; ++mtd)
        #pragma unroll
        for (int rr = 0; rr < 4; ++rr) {
            int d = mtd * 16 + quad * 4 + rr;
            ob[(size_t)d * 1024 + l15] = f2bf(accO[mtd][rr]);
        }
    if (quad == 0)
        LP[((size_t)jh * 64 + bh) * 1024 + i0 + wv * 16 + l15] = l_i;
}

// =====================================================================
extern "C" void kernel_launch(void* const* d_in, const int* in_sizes, int n_in,
                              void* d_out, int out_size, void* d_ws, size_t ws_size,
                              hipStream_t stream)
{
    const float* x      = (const float*)d_in[0];
    const float* gn_w   = (const float*)d_in[1];
    const float* gn_b   = (const float*)d_in[2];
    const float* qkv_w  = (const float*)d_in[3];
    const float* qkv_b  = (const float*)d_in[4];
    const float* proj_w = (const float*)d_in[5];
    const float* proj_b = (const float*)d_in[6];
    float* out = (float*)d_out;

    // ws: y16 8.4MB | w16q 384KB | w16p 128KB | qT/kT/vN 8MB each |
    //     OP 16.8MB | LP 512KB   (~50 MB total)
    char* ws = (char*)d_ws;
    unsigned short* y16  = (unsigned short*)ws;
    unsigned short* w16q = y16 + (size_t)B_ * C_ * HW_;
    unsigned short* w16p = w16q + 768 * 256;
    unsigned short* qT   = w16p + 256 * 256;
    unsigned short* kT   = qT + (size_t)B_ * NH_ * HW_ * 64;
    unsigned short* vN   = kT + (size_t)B_ * NH_ * HW_ * 64;
    unsigned short* OP   = vN + (size_t)B_ * C_ * HW_;
    float*          LP   = (float*)(OP + (size_t)2 * B_ * C_ * HW_);
    (void)in_sizes; (void)n_in; (void)out_size; (void)ws_size;

    gn_wcvt_kernel<<<dim3(768), 256, 0, stream>>>(
        x, gn_w, gn_b, y16, qkv_w, proj_w, w16q, w16p);

    qkv_mfma_kernel<<<dim3(HW_ / 64, 6, B_), 256, 0, stream>>>(
        w16q, y16, qkv_b, qT, kT, vN);

    attn_mfma_kernel<<<dim3(NH_ * B_, HW_ / 64, 2), 256, 0, stream>>>(qT, kT, vN, OP, LP);

    proj_mfma_kernel<<<dim3(HW_ / 64, C_ / 64, B_), 256, 0, stream>>>(
        w16p, OP, LP, proj_b, x, out);
}